// Round 7
// baseline (468.942 us; speedup 1.0000x reference)
//
#include <hip/hip_runtime.h>

#define N_EDGES 160000
#define C_EMB 32
#define N_RBF 32
#define Z_MAX 119

typedef float floatx4 __attribute__((ext_vector_type(4)));

#define PI_F 3.14159265358979323f
#define RSZ ((size_t)N_EDGES * 288)

// =========================== K0: F/G pair tables ==============================
__global__ __launch_bounds__(256) void k0_tables(
    const float* __restrict__ zt,   // (119, 32)
    const float* __restrict__ zw,   // (32, 64) row-major
    float* __restrict__ FG)         // F=[0,3808), G=[3808,7616)
{
    int i = blockIdx.x * 256 + threadIdx.x;
    if (i >= 2 * Z_MAX * C_EMB) return;
    int which = i / (Z_MAX * C_EMB);
    int j = i - which * Z_MAX * C_EMB;
    int z = j >> 5, cc = j & 31;
    const float* wrow = zw + cc * 64 + which * 32;
    const float* zrow = zt + z * 32;
    float acc = 0.0f;
    #pragma unroll
    for (int k = 0; k < 32; ++k) acc += zrow[k] * wrow[k];
    FG[i] = acc;
}

// ===================== kA: per-edge compact record (128 fl) ===================
// rec[e][0..95] = c (env & h_z folded), rec[e][96..122] = basis27
#define EPA 64
#define TA 256

__global__ __launch_bounds__(TA) void kA_features(
    const int* __restrict__ atomic_numbers,
    const int* __restrict__ nbr,
    const float* __restrict__ ev,
    const float* __restrict__ dense_W,     // (96, 32)
    const float* __restrict__ dense_b,     // (96,)
    const float* __restrict__ rbf_beta,
    const float* __restrict__ rbf_centres,
    const float* __restrict__ FG,
    float* __restrict__ rec)               // (N_EDGES, 128)
{
    __shared__ int   s_zi[EPA];
    __shared__ int   s_zj[EPA];
    __shared__ float s_rbf[EPA][N_RBF];
    __shared__ float s_env[EPA];

    const int tid = threadIdx.x;
    const int e0 = blockIdx.x * EPA;

    if (tid < EPA)            s_zi[tid]       = atomic_numbers[nbr[e0 + tid]];
    else if (tid < 2 * EPA)   s_zj[tid - EPA] = atomic_numbers[nbr[N_EDGES + e0 + tid - EPA]];

    for (int idx = tid; idx < EPA * N_RBF; idx += TA) {
        int e = idx >> 5, n = idx & 31, ge = e0 + e;
        float x = ev[ge * 3 + 0], y = ev[ge * 3 + 1], z = ev[ge * 3 + 2];
        float r = sqrtf(x * x + y * y + z * z);
        float d = __expf(-r) - rbf_centres[n];
        s_rbf[e][n] = __expf(-rbf_beta[n] * d * d);
        if (n == 0)
            s_env[e] = (r < 5.0f) ? 0.5f * (__cosf(PI_F * r * 0.2f) + 1.0f) : 0.0f;
    }

    for (int idx = tid; idx < EPA * 27; idx += TA) {
        int e = idx / 27, t = idx - e * 27, ge = e0 + e;
        float x = ev[ge * 3 + 0], y = ev[ge * 3 + 1], z = ev[ge * 3 + 2];
        float rinv = rsqrtf(x * x + y * y + z * z);
        float vx = x * rinv, vy = y * rinv, vz = z * rinv;
        float val;
        if (t < 9) {
            val = (t == 0 || t == 4 || t == 8) ? 1.0f : 0.0f;
        } else if (t < 18) {
            int p = t - 9;
            switch (p) {
                case 1: val = -vz; break;
                case 2: val =  vy; break;
                case 3: val =  vz; break;
                case 5: val = -vx; break;
                case 6: val = -vy; break;
                case 7: val =  vx; break;
                default: val = 0.0f; break;
            }
        } else {
            int p = t - 18;
            int i = p / 3, j = p - 3 * i;
            float ri = (i == 0) ? vx : ((i == 1) ? vy : vz);
            float rj = (j == 0) ? vx : ((j == 1) ? vy : vz);
            val = ri * rj - ((i == j) ? (1.0f / 3.0f) : 0.0f);
        }
        rec[(size_t)ge * 128 + 96 + t] = val;
    }
    __syncthreads();

    const float* Ft = FG;
    const float* Gt = FG + Z_MAX * C_EMB;
    for (int idx = tid; idx < EPA * 96; idx += TA) {
        int e = idx / 96, m = idx - e * 96, ge = e0 + e;
        int cc = m & 31;
        const float4* Wd  = (const float4*)(dense_W + m * 32);
        const float4* rb4 = (const float4*)s_rbf[e];
        float acc = dense_b[m];
        #pragma unroll
        for (int n = 0; n < 8; ++n) {
            float4 w = Wd[n]; float4 rv = rb4[n];
            acc += w.x * rv.x + w.y * rv.y + w.z * rv.z + w.w * rv.w;
        }
        float hz = Ft[s_zi[e] * 32 + cc] + Gt[s_zj[e] * 32 + cc];
        rec[(size_t)ge * 128 + m] = acc * s_env[e] * hz;
    }
}

// ========== kB: LDS-free, barrier-free, register-fed store stream =============
// One wave = one edge per iteration. Per-lane index tables precomputed.
// Per edge: ~20 independent L1-resident scalar loads -> muls -> 3 full-wave
// 1KB contiguous stores + 3 predicated 128B tail stores. No DS ops at all.
#define TB 256
#define NB 2048

__global__ __launch_bounds__(TB) void kB_expand(
    const float* __restrict__ rec,   // (N_EDGES, 128)
    float* __restrict__ out)
{
    const int lane = threadIdx.x & 63;
    const int gw   = (blockIdx.x * TB + threadIdx.x) >> 6;
    const int NW   = NB * (TB >> 6);            // 8192 waves

    // per-lane constant tables: set 0 -> fl4 q=lane; set 1 -> q=64+lane (lane<8)
    int cbase[2];        // cc of first element
    int sel[2][4];       // 0/1: use cbase or cbase+1
    int pp[2][4];        // p index (0..8)
    #pragma unroll
    for (int s = 0; s < 2; ++s) {
        int q = s * 64 + lane;
        if (q >= 72) q = 71;          // clamp; such lanes never store set1
        int f0 = 4 * q;
        cbase[s] = f0 / 9;
        #pragma unroll
        for (int u = 0; u < 4; ++u) {
            int f = f0 + u;
            int c = f / 9;
            sel[s][u] = c - cbase[s];
            pp[s][u]  = f - 9 * c;
        }
    }
    const bool t1 = (lane < 8);

    for (int e = gw; e < N_EDGES; e += NW) {
        const float* row = rec + (size_t)e * 128;

        // -------- gather (all independent scalar loads, L1-resident row) -----
        float c0a[3], c0b[3], b0[3][4];
        #pragma unroll
        for (int r = 0; r < 3; ++r) {
            c0a[r] = row[32 * r + cbase[0]];
            c0b[r] = row[32 * r + cbase[0] + 1];
            #pragma unroll
            for (int u = 0; u < 4; ++u)
                b0[r][u] = row[96 + 9 * r + pp[0][u]];
        }
        float c1a[3], c1b[3], b1[3][4];
        if (t1) {
            #pragma unroll
            for (int r = 0; r < 3; ++r) {
                c1a[r] = row[32 * r + cbase[1]];
                c1b[r] = row[32 * r + cbase[1] + 1];
                #pragma unroll
                for (int u = 0; u < 4; ++u)
                    b1[r][u] = row[96 + 9 * r + pp[1][u]];
            }
        }

        // -------- compute + store (3 full-wave 1KB stores + 3 tail stores) ---
        #pragma unroll
        for (int r = 0; r < 3; ++r) {
            float* ob = out + (size_t)r * RSZ + (size_t)e * 288;
            floatx4 v;
            #pragma unroll
            for (int u = 0; u < 4; ++u)
                v[u] = (sel[0][u] ? c0b[r] : c0a[r]) * b0[r][u];
            *(floatx4*)(ob + 4 * lane) = v;
            if (t1) {
                floatx4 w;
                #pragma unroll
                for (int u = 0; u < 4; ++u)
                    w[u] = (sel[1][u] ? c1b[r] : c1a[r]) * b1[r][u];
                *(floatx4*)(ob + 256 + 4 * lane) = w;
            }
        }
    }
}

// ===================== Fallback: proven R1 single kernel ======================
#define EPBF 16
#define TF 256

__global__ __launch_bounds__(TF) void edge_embed_fallback(
    const int* __restrict__ atomic_numbers,
    const int* __restrict__ nbr,
    const float* __restrict__ ev,
    const float* __restrict__ z_table,
    const float* __restrict__ z_map_W,
    const float* __restrict__ dense_W,
    const float* __restrict__ dense_b,
    const float* __restrict__ rbf_beta,
    const float* __restrict__ rbf_centres,
    float* __restrict__ out)
{
    __shared__ float s_hi[EPBF][C_EMB];
    __shared__ float s_hj[EPBF][C_EMB];
    __shared__ float s_rbf[EPBF][N_RBF];
    __shared__ float s_hz[EPBF][C_EMB];
    __shared__ float s_c[EPBF][96];
    __shared__ float s_basis[EPBF][28];

    const int tid = threadIdx.x;
    const int e0 = blockIdx.x * EPBF;

    for (int idx = tid; idx < EPBF * C_EMB; idx += TF) {
        int e = idx >> 5, k = idx & 31, ge = e0 + e;
        s_hi[e][k] = z_table[atomic_numbers[nbr[ge]] * C_EMB + k];
        s_hj[e][k] = z_table[atomic_numbers[nbr[N_EDGES + ge]] * C_EMB + k];
    }
    for (int idx = tid; idx < EPBF * N_RBF; idx += TF) {
        int e = idx >> 5, n = idx & 31, ge = e0 + e;
        float x = ev[ge * 3 + 0], y = ev[ge * 3 + 1], z = ev[ge * 3 + 2];
        float r = sqrtf(x * x + y * y + z * z);
        float d = __expf(-r) - rbf_centres[n];
        s_rbf[e][n] = __expf(-rbf_beta[n] * d * d);
        if (n == 0)
            s_basis[e][27] = (r < 5.0f) ? 0.5f * (__cosf(PI_F * r * 0.2f) + 1.0f) : 0.0f;
    }
    for (int idx = tid; idx < EPBF * 27; idx += TF) {
        int e = idx / 27, t = idx - e * 27, ge = e0 + e;
        float x = ev[ge * 3 + 0], y = ev[ge * 3 + 1], z = ev[ge * 3 + 2];
        float rinv = rsqrtf(x * x + y * y + z * z);
        float vx = x * rinv, vy = y * rinv, vz = z * rinv;
        float val;
        if (t < 9) val = (t == 0 || t == 4 || t == 8) ? 1.0f : 0.0f;
        else if (t < 18) {
            int p = t - 9;
            switch (p) {
                case 1: val = -vz; break;
                case 2: val =  vy; break;
                case 3: val =  vz; break;
                case 5: val = -vx; break;
                case 6: val = -vy; break;
                case 7: val =  vx; break;
                default: val = 0.0f; break;
            }
        } else {
            int p = t - 18;
            int i = p / 3, j = p - 3 * i;
            float ri = (i == 0) ? vx : ((i == 1) ? vy : vz);
            float rj = (j == 0) ? vx : ((j == 1) ? vy : vz);
            val = ri * rj - ((i == j) ? (1.0f / 3.0f) : 0.0f);
        }
        s_basis[e][t] = val;
    }
    __syncthreads();
    for (int idx = tid; idx < EPBF * C_EMB; idx += TF) {
        int e = idx >> 5, cc = idx & 31;
        const float4* Wi  = (const float4*)(z_map_W + cc * 64);
        const float4* hi4 = (const float4*)s_hi[e];
        const float4* hj4 = (const float4*)s_hj[e];
        float acc = 0.0f;
        #pragma unroll
        for (int k = 0; k < 8; ++k) {
            float4 w = Wi[k]; float4 h = hi4[k];
            acc += w.x * h.x + w.y * h.y + w.z * h.z + w.w * h.w;
        }
        #pragma unroll
        for (int k = 0; k < 8; ++k) {
            float4 w = Wi[8 + k]; float4 h = hj4[k];
            acc += w.x * h.x + w.y * h.y + w.z * h.z + w.w * h.w;
        }
        s_hz[e][cc] = acc;
    }
    __syncthreads();
    for (int idx = tid; idx < EPBF * 96; idx += TF) {
        int e = idx / 96, m = idx - e * 96;
        int cc = m & 31;
        const float4* Wd  = (const float4*)(dense_W + m * 32);
        const float4* rb4 = (const float4*)s_rbf[e];
        float acc = dense_b[m];
        #pragma unroll
        for (int n = 0; n < 8; ++n) {
            float4 w = Wd[n]; float4 rv = rb4[n];
            acc += w.x * rv.x + w.y * rv.y + w.z * rv.z + w.w * rv.w;
        }
        s_c[e][m] = acc * s_basis[e][27] * s_hz[e][cc];
    }
    __syncthreads();
    float* outI = out + (size_t)e0 * 288;
    float* outA = out + RSZ + (size_t)e0 * 288;
    float* outS = out + 2 * RSZ + (size_t)e0 * 288;
    const int NQ = EPBF * 288 / 4;
    for (int q = tid; q < NQ; q += TF) {
        int fbase = q * 4;
        floatx4 aI, aA, aS;
        #pragma unroll
        for (int u = 0; u < 4; ++u) {
            int f = fbase + u;
            int e = f / 288;
            int rem = f - e * 288;
            int cc = rem / 9;
            int p = rem - cc * 9;
            aI[u] = s_c[e][cc]      * s_basis[e][p];
            aA[u] = s_c[e][32 + cc] * s_basis[e][9 + p];
            aS[u] = s_c[e][64 + cc] * s_basis[e][18 + p];
        }
        ((floatx4*)outI)[q] = aI;
        ((floatx4*)outA)[q] = aA;
        ((floatx4*)outS)[q] = aS;
    }
}

extern "C" void kernel_launch(void* const* d_in, const int* in_sizes, int n_in,
                              void* d_out, int out_size, void* d_ws, size_t ws_size,
                              hipStream_t stream) {
    const int*   an  = (const int*)d_in[0];
    const int*   nbr = (const int*)d_in[1];
    const float* ev  = (const float*)d_in[2];
    const float* zt  = (const float*)d_in[3];
    const float* zw  = (const float*)d_in[4];
    const float* dw  = (const float*)d_in[5];
    const float* db  = (const float*)d_in[6];
    const float* rb  = (const float*)d_in[7];
    const float* rc  = (const float*)d_in[8];
    float* outp = (float*)d_out;

    const size_t rec_f = (size_t)N_EDGES * 128;
    const size_t fg_f  = 2 * Z_MAX * C_EMB;
    const size_t need  = (rec_f + fg_f) * sizeof(float);

    if (ws_size >= need) {
        float* rec = (float*)d_ws;
        float* FG  = rec + rec_f;
        k0_tables<<<dim3((2 * Z_MAX * C_EMB + 255) / 256), 256, 0, stream>>>(zt, zw, FG);
        kA_features<<<dim3(N_EDGES / EPA), TA, 0, stream>>>(
            an, nbr, ev, dw, db, rb, rc, FG, rec);
        kB_expand<<<dim3(NB), TB, 0, stream>>>(rec, outp);
    } else {
        edge_embed_fallback<<<dim3(N_EDGES / EPBF), TF, 0, stream>>>(
            an, nbr, ev, zt, zw, dw, db, rb, rc, outp);
    }
}